// Round 7
// baseline (352.200 us; speedup 1.0000x reference)
//
#include <hip/hip_runtime.h>

#define NA 50000
#define NT 25000
#define EAA 800000
#define EAT 400000
#define ETA 400000
#define NSEG 125000          // NA + NA + NT rows: [aa | ta | at]
#define TOTAL_E 1600000
#define NB 245               // coarse buckets of 512 rows
#define NBLK1 196            // pass-1 blocks
#define CHUNK 8192           // edges per pass-1 block
#define GA 1024              // conv1 agent blocks
#define GT 512               // conv1 target blocks

// ---- workspace layout (4-byte element offsets) ----
#define O_HIST    0          // int[48020]: hist[bucket][block] -> scanned bases
#define O_ATSRC   48064      // int[50000]: at-relation src out-degree (over NA)
#define O_TASRC   98064      // int[25000]: ta-relation src out-degree (over NT)
#define O_RO      123072     // int[125001]: CSR row offsets
#define O_CAA     248128     // float[50000]: rsqrt(indeg_aa+1)
#define O_CTAD    298128     // float[50000]: ta dst coef (over NA)
#define O_CATD    348128     // float[25000]: at dst coef (over NT)
#define O_CATS    373128     // float[50000]: at src coef (over NA)
#define O_CTAS    423128     // float[25000]: ta src coef (over NT)
#define O_U       448128     // float[512]: U_aa[128] | U_ta[128] | U_at[128] | v[4]
#define O_P       448640     // float[100000]: p' = (h_a @ U_aa) * c_aa
#define O_Q       548640     // float[100000]: q' = (h_a @ U_at) * c_ats
#define O_R       648640     // float[50000]:  r' = (h_t @ U_ta) * c_tas
#define O_REC     698640     // int[1600000]: packed records (row_local<<16)|src
#define O_CSR     2298640    // ushort[1600000]: final CSR src indices (800000 ints)
#define O_XWAA    3098640    // float[1600000]: x_a * c_aa
#define O_XWAT    4698640    // float[1600000]: x_a * c_at_s
#define O_XWTT    6298640    // float[800000]:  x_t * c_ta_s
// total 7,098,640 elems = 28.4 MB

// ---------- pass 1a: per-block coarse histogram (LDS) + fused src-degree atomics ----------
__global__ void __launch_bounds__(256)
p1_hist_kernel(const int* __restrict__ dst_aa, const int* __restrict__ dst_ta,
               const int* __restrict__ dst_at, const int* __restrict__ src_ta,
               const int* __restrict__ src_at, int* __restrict__ wi) {
    __shared__ int h[NB];
    for (int i = threadIdx.x; i < NB; i += 256) h[i] = 0;
    __syncthreads();
    int b = blockIdx.x;
    int t0 = b * CHUNK, t1 = min(t0 + CHUNK, TOTAL_E);
    for (int t = t0 + threadIdx.x; t < t1; t += 256) {
        int row;
        if (t < EAA) {
            row = dst_aa[t];
        } else if (t < EAA + ETA) {
            int u = t - EAA;
            row = NA + dst_ta[u];
            atomicAdd(&wi[O_TASRC + src_ta[u]], 1);
        } else {
            int u = t - EAA - ETA;
            row = 2 * NA + dst_at[u];
            atomicAdd(&wi[O_ATSRC + src_at[u]], 1);
        }
        atomicAdd(&h[row >> 9], 1);
    }
    __syncthreads();
    for (int i = threadIdx.x; i < NB; i += 256) wi[O_HIST + i * NBLK1 + b] = h[i];
}

// ---------- aux: block 0 = hist scan; blocks 1..74 = src coefs; block 75 = U fuse ----------
__global__ void __launch_bounds__(1024)
aux_kernel(int* __restrict__ wi, float* __restrict__ wf,
           const float* __restrict__ W2_aa, const float* __restrict__ W2_ta,
           const float* __restrict__ W2_at, const float* __restrict__ b2_aa,
           const float* __restrict__ b2_ta, const float* __restrict__ b2_at,
           const float* __restrict__ Wp_a, const float* __restrict__ bp_a,
           const float* __restrict__ Wp_t, const float* __restrict__ bp_t) {
    if (blockIdx.x == 0) {
        __shared__ int wsum[16];
        __shared__ int sCarry;
        int* h = wi + O_HIST;
        int tid = threadIdx.x, lane = tid & 63, wid = tid >> 6;
        if (tid == 0) sCarry = 0;
        __syncthreads();
        const int N2 = NB * NBLK1;
        for (int base = 0; base < N2; base += 1024) {
            int idx = base + tid;
            int v = (idx < N2) ? h[idx] : 0;
            int x = v;
#pragma unroll
            for (int off = 1; off < 64; off <<= 1) {
                int y = __shfl_up(x, off, 64);
                if (lane >= off) x += y;
            }
            if (lane == 63) wsum[wid] = x;
            __syncthreads();
            int wpre = 0, tot = 0;
            for (int w = 0; w < 16; ++w) {
                int s = wsum[w];
                if (w < wid) wpre += s;
                tot += s;
            }
            int excl = x - v + wpre + sCarry;
            if (idx < N2) h[idx] = excl;
            __syncthreads();
            if (tid == 0) sCarry += tot;
            __syncthreads();
        }
    } else if (blockIdx.x <= 74) {
        int t = (blockIdx.x - 1) * 1024 + threadIdx.x;
        if (t < 50000) {
            int d = wi[O_ATSRC + t];
            wf[O_CATS + t] = d > 0 ? rsqrtf((float)d) : 0.0f;
        } else if (t < 75000) {
            int i = t - 50000; int d = wi[O_TASRC + i];
            wf[O_CTAS + i] = d > 0 ? rsqrtf((float)d) : 0.0f;
        }
    } else {
        float* U = wf + O_U;
        int t = threadIdx.x;
        if (t < 128) {
            int k = t >> 1, j = t & 1;
            float a = 0.f;
            for (int f = 0; f < 64; ++f) a = fmaf(W2_aa[k * 64 + f], Wp_a[f * 2 + j], a);
            U[t] = a;
        } else if (t < 256) {
            int u = t - 128; int k = u >> 1, j = u & 1;
            float a = 0.f;
            for (int f = 0; f < 64; ++f) a = fmaf(W2_ta[k * 64 + f], Wp_a[f * 2 + j], a);
            U[128 + u] = a;
        } else if (t < 384) {
            int u = t - 256; int k = u >> 1, j = u & 1;
            float a = 0.f;
            for (int f = 0; f < 64; ++f) a = fmaf(W2_at[k * 64 + f], Wp_t[f * 2 + j], a);
            U[256 + u] = a;
        } else if (t < 386) {
            int j = t - 384;
            float a = bp_a[j];
            for (int f = 0; f < 64; ++f) a = fmaf(b2_aa[f] + b2_ta[f], Wp_a[f * 2 + j], a);
            U[384 + j] = a;
        } else if (t < 388) {
            int j = t - 386;
            float a = bp_t[j];
            for (int f = 0; f < 64; ++f) a = fmaf(b2_at[f], Wp_t[f * 2 + j], a);
            U[386 + j] = a;
        }
    }
}

// ---------- pass 1c: scatter packed records via LDS cursors (block-exclusive runs) ----------
__global__ void __launch_bounds__(256)
p1_scatter_kernel(const int* __restrict__ src_aa, const int* __restrict__ dst_aa,
                  const int* __restrict__ src_ta, const int* __restrict__ dst_ta,
                  const int* __restrict__ src_at, const int* __restrict__ dst_at,
                  const int* __restrict__ hist_g, int* __restrict__ rec) {
    __shared__ int cur[NB];
    int b = blockIdx.x;
    for (int i = threadIdx.x; i < NB; i += 256) cur[i] = hist_g[i * NBLK1 + b];
    __syncthreads();
    int t0 = b * CHUNK, t1 = min(t0 + CHUNK, TOTAL_E);
    for (int t = t0 + threadIdx.x; t < t1; t += 256) {
        int row, s;
        if (t < EAA) { row = dst_aa[t]; s = src_aa[t]; }
        else if (t < EAA + ETA) { int u = t - EAA; row = NA + dst_ta[u]; s = src_ta[u]; }
        else { int u = t - EAA - ETA; row = 2 * NA + dst_at[u]; s = src_at[u]; }
        int pos = atomicAdd(&cur[row >> 9], 1);
        rec[pos] = ((row & 511) << 16) | s;
    }
}

// ---------- pass 2: per-bucket degree count + LDS scan -> ro + dst coefs + CSR scatter ----------
__global__ void __launch_bounds__(256)
p2_kernel(const int* __restrict__ hist_g, const int* __restrict__ rec,
          int* __restrict__ ro, float* __restrict__ caa, float* __restrict__ ctad,
          float* __restrict__ catd, unsigned short* __restrict__ csr) {
    __shared__ int deg[512];
    __shared__ int rb[512];
    __shared__ int wsum[4];
    int k = blockIdx.x, tid = threadIdx.x, lane = tid & 63, wid = tid >> 6;
    int e0 = hist_g[k * NBLK1];
    int e1 = (k + 1 < NB) ? hist_g[(k + 1) * NBLK1] : TOTAL_E;
    deg[tid] = 0; deg[tid + 256] = 0;
    __syncthreads();
    for (int j = e0 + tid; j < e1; j += 256) atomicAdd(&deg[rec[j] >> 16], 1);
    __syncthreads();
    int d0 = deg[2 * tid], d1 = deg[2 * tid + 1];
    int v = d0 + d1;
    int x = v;
#pragma unroll
    for (int off = 1; off < 64; off <<= 1) {
        int y = __shfl_up(x, off, 64);
        if (lane >= off) x += y;
    }
    if (lane == 63) wsum[wid] = x;
    __syncthreads();
    int wpre = 0;
    for (int w = 0; w < wid; ++w) wpre += wsum[w];
    int pexcl = x - v + wpre;
    rb[2 * tid] = e0 + pexcl;
    rb[2 * tid + 1] = e0 + pexcl + d0;
    __syncthreads();
    for (int i = tid; i < 512; i += 256) {
        int g = k * 512 + i;
        if (g < NSEG) {
            ro[g] = rb[i];
            int d = deg[i];
            if (g < NA) caa[g] = rsqrtf((float)d + 1.0f);
            else if (g < 2 * NA) ctad[g - NA] = d > 0 ? rsqrtf((float)d) : 0.0f;
            else catd[g - 2 * NA] = d > 0 ? rsqrtf((float)d) : 0.0f;
        }
    }
    if (k == NB - 1 && tid == 0) ro[NSEG] = TOTAL_E;
    __syncthreads();
    for (int j = e0 + tid; j < e1; j += 256) {
        int rc = rec[j];
        int pos = atomicAdd(&rb[rc >> 16], 1);
        csr[pos] = (unsigned short)(rc & 0xFFFF);
    }
}

// ---------- premultiply x rows by src-side coefficients (coalesced float4) ----------
__global__ void __launch_bounds__(256)
premul_kernel(const float* __restrict__ x_a, const float* __restrict__ x_t,
              const float* __restrict__ c_aa, const float* __restrict__ c_at_s,
              const float* __restrict__ c_ta_s, float* __restrict__ xwAA,
              float* __restrict__ xwAT, float* __restrict__ xwTT) {
    int t = blockIdx.x * 256 + threadIdx.x;   // float4 index
    if (t < 400000) {
        float c = c_aa[t >> 3];
        float4 xv = ((const float4*)x_a)[t];
        xv.x *= c; xv.y *= c; xv.z *= c; xv.w *= c;
        ((float4*)xwAA)[t] = xv;
    } else if (t < 800000) {
        int u = t - 400000;
        float c = c_at_s[u >> 3];
        float4 xv = ((const float4*)x_a)[u];
        xv.x *= c; xv.y *= c; xv.z *= c; xv.w *= c;
        ((float4*)xwAT)[u] = xv;
    } else if (t < 1000000) {
        int u = t - 800000;
        float c = c_ta_s[u >> 3];
        float4 xv = ((const float4*)x_t)[u];
        xv.x *= c; xv.y *= c; xv.z *= c; xv.w *= c;
        ((float4*)xwTT)[u] = xv;
    }
}

// ---------- conv1: register-weights + shfl-agg matvec, grid-stride nodes, zero LDS ----------
__global__ void __launch_bounds__(256)
conv1_all_kernel(const float* __restrict__ xwAA, const float* __restrict__ xwTT,
                 const float* __restrict__ xwAT,
                 const int* __restrict__ ro, const unsigned short* __restrict__ csr,
                 const float* __restrict__ c_aa, const float* __restrict__ c_ta_d,
                 const float* __restrict__ c_ta_s, const float* __restrict__ c_at_s,
                 const float* __restrict__ c_at_d,
                 const float* __restrict__ W_aa, const float* __restrict__ b_aa,
                 const float* __restrict__ W_ta, const float* __restrict__ b_ta,
                 const float* __restrict__ W_at, const float* __restrict__ b_at,
                 const float* __restrict__ U,
                 float* __restrict__ p, float* __restrict__ q, float* __restrict__ r) {
    int lane = threadIdx.x & 63;
    int wave = threadIdx.x >> 6;
    int e8 = lane >> 3, k4 = lane & 7;

    if (blockIdx.x < GA) {
        // ---------- agents ----------
        float wA[32], wT[32];
#pragma unroll
        for (int k = 0; k < 32; ++k) {
            wA[k] = W_aa[k * 64 + lane];
            wT[k] = W_ta[k * 64 + lane];
        }
        float bias = b_aa[lane] + b_ta[lane];
        float uP0 = U[lane * 2], uP1 = U[lane * 2 + 1];
        float uQ0 = U[256 + lane * 2], uQ1 = U[256 + lane * 2 + 1];
        for (int i = blockIdx.x * 4 + wave; i < NA; i += GA * 4) {
            int b0 = ro[i], n0 = ro[i + 1] - b0;
            int b1 = ro[NA + i], n1 = ro[NA + i + 1] - b1;
            int sA = (lane < n0) ? (int)csr[b0 + lane] : -1;
            int sT = (lane < n1) ? (int)csr[b1 + lane] : -1;
            float4 accA = make_float4(0.f, 0.f, 0.f, 0.f);
            float4 accT = make_float4(0.f, 0.f, 0.f, 0.f);
            int ngA = min(n0, 64);
            for (int g = 0; g * 8 < ngA; ++g) {
                int s = __shfl(sA, g * 8 + e8, 64);
                if (s >= 0) {
                    float4 xv = *(const float4*)(xwAA + (size_t)s * 32 + k4 * 4);
                    accA.x += xv.x; accA.y += xv.y; accA.z += xv.z; accA.w += xv.w;
                }
            }
            for (int j = b0 + 64 + e8; j < b0 + n0; j += 8) {   // rare tail
                float4 xv = *(const float4*)(xwAA + (size_t)csr[j] * 32 + k4 * 4);
                accA.x += xv.x; accA.y += xv.y; accA.z += xv.z; accA.w += xv.w;
            }
            if (e8 == 0) {  // self-loop (xwAA already has c_aa[i] factor)
                float4 xv = *(const float4*)(xwAA + (size_t)i * 32 + k4 * 4);
                accA.x += xv.x; accA.y += xv.y; accA.z += xv.z; accA.w += xv.w;
            }
            int ngT = min(n1, 64);
            for (int g = 0; g * 8 < ngT; ++g) {
                int s = __shfl(sT, g * 8 + e8, 64);
                if (s >= 0) {
                    float4 xv = *(const float4*)(xwTT + (size_t)s * 32 + k4 * 4);
                    accT.x += xv.x; accT.y += xv.y; accT.z += xv.z; accT.w += xv.w;
                }
            }
            for (int j = b1 + 64 + e8; j < b1 + n1; j += 8) {   // rare tail
                float4 xv = *(const float4*)(xwTT + (size_t)csr[j] * 32 + k4 * 4);
                accT.x += xv.x; accT.y += xv.y; accT.z += xv.z; accT.w += xv.w;
            }
#pragma unroll
            for (int m = 8; m <= 32; m <<= 1) {
                accA.x += __shfl_xor(accA.x, m, 64);
                accA.y += __shfl_xor(accA.y, m, 64);
                accA.z += __shfl_xor(accA.z, m, 64);
                accA.w += __shfl_xor(accA.w, m, 64);
                accT.x += __shfl_xor(accT.x, m, 64);
                accT.y += __shfl_xor(accT.y, m, 64);
                accT.z += __shfl_xor(accT.z, m, 64);
                accT.w += __shfl_xor(accT.w, m, 64);
            }
            // lane (any) holds slice (lane&7); broadcast slices g=0..7 via shfl
            float hA = 0.f, hT = 0.f;
#pragma unroll
            for (int g = 0; g < 8; ++g) {
                float a0 = __shfl(accA.x, g, 64), a1 = __shfl(accA.y, g, 64);
                float a2 = __shfl(accA.z, g, 64), a3 = __shfl(accA.w, g, 64);
                hA = fmaf(a0, wA[4 * g], hA);
                hA = fmaf(a1, wA[4 * g + 1], hA);
                hA = fmaf(a2, wA[4 * g + 2], hA);
                hA = fmaf(a3, wA[4 * g + 3], hA);
                float t0v = __shfl(accT.x, g, 64), t1v = __shfl(accT.y, g, 64);
                float t2v = __shfl(accT.z, g, 64), t3v = __shfl(accT.w, g, 64);
                hT = fmaf(t0v, wT[4 * g], hT);
                hT = fmaf(t1v, wT[4 * g + 1], hT);
                hT = fmaf(t2v, wT[4 * g + 2], hT);
                hT = fmaf(t3v, wT[4 * g + 3], hT);
            }
            float ci = c_aa[i];
            float h = fmaxf(bias + ci * hA + c_ta_d[i] * hT, 0.f);
            float p0 = h * uP0, p1 = h * uP1, q0 = h * uQ0, q1 = h * uQ1;
#pragma unroll
            for (int m = 32; m; m >>= 1) {
                p0 += __shfl_xor(p0, m, 64);
                p1 += __shfl_xor(p1, m, 64);
                q0 += __shfl_xor(q0, m, 64);
                q1 += __shfl_xor(q1, m, 64);
            }
            if (lane == 0) {
                float cq = c_at_s[i];
                *(float2*)&p[i * 2] = make_float2(p0 * ci, p1 * ci);
                *(float2*)&q[i * 2] = make_float2(q0 * cq, q1 * cq);
            }
        }
    } else {
        // ---------- targets ----------
        float wA[32];
#pragma unroll
        for (int k = 0; k < 32; ++k) wA[k] = W_at[k * 64 + lane];
        float bias = b_at[lane];
        float uR0 = U[128 + lane * 2], uR1 = U[128 + lane * 2 + 1];
        for (int i = (blockIdx.x - GA) * 4 + wave; i < NT; i += GT * 4) {
            int b0 = ro[2 * NA + i], n0 = ro[2 * NA + i + 1] - b0;
            int sA = (lane < n0) ? (int)csr[b0 + lane] : -1;
            float4 acc = make_float4(0.f, 0.f, 0.f, 0.f);
            int ng = min(n0, 64);
            for (int g = 0; g * 8 < ng; ++g) {
                int s = __shfl(sA, g * 8 + e8, 64);
                if (s >= 0) {
                    float4 xv = *(const float4*)(xwAT + (size_t)s * 32 + k4 * 4);
                    acc.x += xv.x; acc.y += xv.y; acc.z += xv.z; acc.w += xv.w;
                }
            }
            for (int j = b0 + 64 + e8; j < b0 + n0; j += 8) {   // rare tail
                float4 xv = *(const float4*)(xwAT + (size_t)csr[j] * 32 + k4 * 4);
                acc.x += xv.x; acc.y += xv.y; acc.z += xv.z; acc.w += xv.w;
            }
#pragma unroll
            for (int m = 8; m <= 32; m <<= 1) {
                acc.x += __shfl_xor(acc.x, m, 64);
                acc.y += __shfl_xor(acc.y, m, 64);
                acc.z += __shfl_xor(acc.z, m, 64);
                acc.w += __shfl_xor(acc.w, m, 64);
            }
            float hA = 0.f;
#pragma unroll
            for (int g = 0; g < 8; ++g) {
                float a0 = __shfl(acc.x, g, 64), a1 = __shfl(acc.y, g, 64);
                float a2 = __shfl(acc.z, g, 64), a3 = __shfl(acc.w, g, 64);
                hA = fmaf(a0, wA[4 * g], hA);
                hA = fmaf(a1, wA[4 * g + 1], hA);
                hA = fmaf(a2, wA[4 * g + 2], hA);
                hA = fmaf(a3, wA[4 * g + 3], hA);
            }
            float h = fmaxf(bias + c_at_d[i] * hA, 0.f);
            float r0 = h * uR0, r1 = h * uR1;
#pragma unroll
            for (int m = 32; m; m >>= 1) {
                r0 += __shfl_xor(r0, m, 64);
                r1 += __shfl_xor(r1, m, 64);
            }
            if (lane == 0) {
                float cr = c_ta_s[i];
                *(float2*)&r[i * 2] = make_float2(r0 * cr, r1 * cr);
            }
        }
    }
}

// ---------- conv2+proj: one wave per node, 32 edge slots x 2 comps ----------
__global__ void __launch_bounds__(256)
out_all_kernel(const float* __restrict__ p, const float* __restrict__ q,
               const float* __restrict__ r, const int* __restrict__ ro,
               const unsigned short* __restrict__ csr,
               const float* __restrict__ c_aa, const float* __restrict__ c_ta_d,
               const float* __restrict__ c_at_d, const float* __restrict__ U,
               float* __restrict__ out) {
    int wgid = blockIdx.x * 4 + (threadIdx.x >> 6);
    int lane = threadIdx.x & 63;
    int slot = lane >> 1, j = lane & 1;
    if (wgid < NA) {
        int i = wgid;
        int b0 = ro[i], n0 = ro[i + 1] - b0;
        float accA = (slot == 0) ? p[i * 2 + j] : 0.f;   // self-loop (p premultiplied)
        for (int e = slot; e < n0; e += 32) accA += p[(int)csr[b0 + e] * 2 + j];
        int b1 = ro[NA + i], n1 = ro[NA + i + 1] - b1;
        float accT = 0.f;
        for (int e = slot; e < n1; e += 32) accT += r[(int)csr[b1 + e] * 2 + j];
#pragma unroll
        for (int m = 2; m <= 32; m <<= 1) {
            accA += __shfl_xor(accA, m, 64);
            accT += __shfl_xor(accT, m, 64);
        }
        if (lane < 2) out[i * 2 + j] = U[384 + j] + accA * c_aa[i] + accT * c_ta_d[i];
    } else {
        int i = wgid - NA;
        int b0 = ro[2 * NA + i], n0 = ro[2 * NA + i + 1] - b0;
        float acc = 0.f;
        for (int e = slot; e < n0; e += 32) acc += q[(int)csr[b0 + e] * 2 + j];
#pragma unroll
        for (int m = 2; m <= 32; m <<= 1) acc += __shfl_xor(acc, m, 64);
        if (lane < 2) out[NA * 2 + i * 2 + j] = U[386 + j] + acc * c_at_d[i];
    }
}

extern "C" void kernel_launch(void* const* d_in, const int* in_sizes, int n_in,
                              void* d_out, int out_size, void* d_ws, size_t ws_size,
                              hipStream_t stream) {
    const float* x_a   = (const float*)d_in[1];
    const float* x_t   = (const float*)d_in[2];
    const int* src_aa  = (const int*)d_in[3];
    const int* dst_aa  = (const int*)d_in[4];
    const int* src_at  = (const int*)d_in[5];
    const int* dst_at  = (const int*)d_in[6];
    const int* src_ta  = (const int*)d_in[7];
    const int* dst_ta  = (const int*)d_in[8];
    const float* W1_aa = (const float*)d_in[9];
    const float* b1_aa = (const float*)d_in[10];
    const float* W1_at = (const float*)d_in[11];
    const float* b1_at = (const float*)d_in[12];
    const float* W1_ta = (const float*)d_in[13];
    const float* b1_ta = (const float*)d_in[14];
    const float* W2_aa = (const float*)d_in[15];
    const float* b2_aa = (const float*)d_in[16];
    const float* W2_at = (const float*)d_in[17];
    const float* b2_at = (const float*)d_in[18];
    const float* W2_ta = (const float*)d_in[19];
    const float* b2_ta = (const float*)d_in[20];
    const float* Wp_a  = (const float*)d_in[21];
    const float* bp_a  = (const float*)d_in[22];
    const float* Wp_t  = (const float*)d_in[23];
    const float* bp_t  = (const float*)d_in[24];

    int*   wi  = (int*)d_ws;
    float* wf  = (float*)d_ws;
    unsigned short* csr = (unsigned short*)(wi + O_CSR);
    float* out = (float*)d_out;

    // zero the src-degree histograms
    hipMemsetAsync(wi + O_ATSRC, 0, 75000 * 4, stream);

    // pass 1: coarse bucket histogram (+ fused src degrees)
    p1_hist_kernel<<<NBLK1, 256, 0, stream>>>(dst_aa, dst_ta, dst_at, src_ta, src_at, wi);

    // scan + src coefs + U fuse in one dispatch
    aux_kernel<<<76, 1024, 0, stream>>>(wi, wf, W2_aa, W2_ta, W2_at, b2_aa, b2_ta, b2_at,
                                        Wp_a, bp_a, Wp_t, bp_t);

    // pass 1c: bucket scatter of packed records
    p1_scatter_kernel<<<NBLK1, 256, 0, stream>>>(src_aa, dst_aa, src_ta, dst_ta,
                                                 src_at, dst_at, wi + O_HIST, wi + O_REC);

    // pass 2: per-bucket -> ro + dst coefs + final CSR
    p2_kernel<<<NB, 256, 0, stream>>>(wi + O_HIST, wi + O_REC, wi + O_RO,
                                      wf + O_CAA, wf + O_CTAD, wf + O_CATD, csr);

    // premultiply x by src coefficients (removes all per-edge weight gathers)
    premul_kernel<<<(1000000 + 255) / 256, 256, 0, stream>>>(
        x_a, x_t, wf + O_CAA, wf + O_CATS, wf + O_CTAS,
        wf + O_XWAA, wf + O_XWAT, wf + O_XWTT);

    // conv1: register-weight matvec, shfl-agg, grid-stride nodes
    conv1_all_kernel<<<GA + GT, 256, 0, stream>>>(
        wf + O_XWAA, wf + O_XWTT, wf + O_XWAT, wi + O_RO, csr,
        wf + O_CAA, wf + O_CTAD, wf + O_CTAS, wf + O_CATS, wf + O_CATD,
        W1_aa, b1_aa, W1_ta, b1_ta, W1_at, b1_at, wf + O_U,
        wf + O_P, wf + O_Q, wf + O_R);

    // conv2 + projection, wave per node
    out_all_kernel<<<(NA + NT) / 4, 256, 0, stream>>>(
        wf + O_P, wf + O_Q, wf + O_R, wi + O_RO, csr,
        wf + O_CAA, wf + O_CTAD, wf + O_CATD, wf + O_U, out);
}